// Round 13
// baseline (167.636 us; speedup 1.0000x reference)
//
#include <hip/hip_runtime.h>
#include <hip/hip_bf16.h>

// NSA forward, MI355X round 23. r16 phase machinery + SPAN REBALANCE:
// attn_k's duration == role0 critical path (cmp + 16 slc ~ 17.5 units);
// role1 idles after cmp + <=9 win units. Fix: role1 takes the last
// s=(17-nwin)>>1 top-k slc tiles after finishing win (win finalized
// mid-loop -> g_winB, state reset); role0 keeps 16-s. Both roles run the
// bit-identical cmp phase (identical pooled -> identical topk); role0
// alone emits the cmp branch (fresh acc -> out). slc halves exported as
// raw gated partials + (m,l) in log2 domain; merge flash-combines and
// sums cmp + win + slc. Grid stays 256 (1 block/CU) -- avoids r20's
// CU-sharing slowdown. Span 17.5 -> ~14.5 units (qb>=8).
// Shapes: S=4096, seqlen=2048, qh=8, kvh=2, dim=128, blk=64, TOPK=16,
// window=(512,0).

#define SEQ   2048
#define NB    2
#define KV    2
#define NH    4
#define QH    8
#define DIM   128
#define NBLK  32
#define NQB   32
#define NTOP  16
#define SCALE 0.08838834764831845f   // 128^-0.5
#define QSC   0.12751831795244785f   // SCALE * log2(e)
#define VP    72                     // P/prep-T LDS row stride (bf16): pad 8
#define VCS   40                     // VcT LDS row stride (bf16): 32 + pad 8

typedef unsigned short ushort_t;
using bf16x8 = __attribute__((ext_vector_type(8))) short;
using f32x4  = __attribute__((ext_vector_type(4))) float;

// partial streams (written by attn_k, read by merge_k)
__device__ float g_slcB[4194304];      // role1 slc partial (16.8 MB)
__device__ float g_winB[4194304];      // role1 win (normalized) (16.8 MB)
__device__ float g_mlg[2][65536];      // slc (m,l) per stream, [rh*2]

__device__ __forceinline__ unsigned pkbf(float a, float b){
  union { __hip_bfloat162 h; unsigned u; } cv;
  cv.h = __float22bfloat162_rn(make_float2(a, b));
  return cv.u;
}
__device__ __forceinline__ ushort_t b16(float f){
  union { float f; unsigned i; } x; x.f = f;
  unsigned r = x.i + 0x7fffu + ((x.i >> 16) & 1u);   // RNE
  return (ushort_t)(r >> 16);
}
__device__ __forceinline__ float fb(ushort_t h){
  union { unsigned i; float f; } x; x.i = ((unsigned)h) << 16;
  return x.f;
}

// async 16B direct-to-LDS copy (per-lane global src, wave-uniform LDS base)
__device__ __forceinline__ void async16(ushort_t* l, const ushort_t* g){
  __builtin_amdgcn_global_load_lds(
      (const __attribute__((address_space(1))) unsigned int*)(size_t)g,
      (__attribute__((address_space(3))) unsigned int*)(size_t)l,
      16, 0, 0);
}

// -------- kernel 0: K/V bf16 preprocessing + block compression (fused) ------
__global__ __launch_bounds__(256) void prep_k(
    const float* __restrict__ k, const float* __restrict__ v,
    const float* __restrict__ w_k, const float* __restrict__ b_k,
    const float* __restrict__ w_v, const float* __restrict__ b_v,
    ushort_t* __restrict__ Kb, ushort_t* __restrict__ VT,
    float* __restrict__ Kc, float* __restrict__ Vc)
{
  int blk = blockIdx.x;
  int db = blk & 1, rb = (blk >> 1) & 31, bbg = blk >> 6;
  int bb = bbg >> 1, g = bbg & 1;
  int tid = threadIdx.x;
  __shared__ ushort_t T[64*VP];    // [d 0..63][key 0..63], pad 8
  __shared__ float wks[64], wvs[64];
  __shared__ float accK[16][64], accV[16][64];

  if (tid < 64){ wks[tid] = w_k[tid]; wvs[tid] = w_v[tid]; }
  __syncthreads();

  float4 sk = {0,0,0,0}, sv = {0,0,0,0};
  for (int jj = 0; jj < 4; ++jj){
    int i = tid + jj*256;                 // 1024 float4 units (64 rows x 16)
    int r = i >> 4, ds = i & 15;
    size_t src = ((size_t)(bb*SEQ + rb*64 + r)*KV + g)*DIM + db*64 + ds*4;
    float4 kx = *(const float4*)(k + src);
    float4 vx = *(const float4*)(v + src);
    uint2 kk; kk.x = pkbf(kx.x,kx.y); kk.y = pkbf(kx.z,kx.w);
    size_t rowb = ((size_t)bbg*SEQ + rb*64 + r)*DIM*2;        // row base bytes
    int swz = (db*128 + ds*8) ^ ((r & 7) << 4);               // within-row
    *(uint2*)((char*)Kb + rowb + swz) = kk;
    unsigned v01 = pkbf(vx.x,vx.y), v23 = pkbf(vx.z,vx.w);
    T[(ds*4+0)*VP + r] = (ushort_t)(v01 & 0xffffu);
    T[(ds*4+1)*VP + r] = (ushort_t)(v01 >> 16);
    T[(ds*4+2)*VP + r] = (ushort_t)(v23 & 0xffffu);
    T[(ds*4+3)*VP + r] = (ushort_t)(v23 >> 16);
    float a = wks[r], b = wvs[r];
    sk.x += a*kx.x; sk.y += a*kx.y; sk.z += a*kx.z; sk.w += a*kx.w;
    sv.x += b*vx.x; sv.y += b*vx.y; sv.z += b*vx.z; sv.w += b*vx.w;
  }
  *(float4*)&accK[tid>>4][(tid&15)*4] = sk;
  *(float4*)&accV[tid>>4][(tid&15)*4] = sv;
  __syncthreads();

  for (int jj = 0; jj < 4; ++jj){
    int i = tid + jj*256;                 // 1024 8B units (64 d x 16)
    int d = i >> 4, seg = i & 15;
    uint2 u = *(uint2*)&T[d*VP + seg*4];
    size_t rowb = ((size_t)bbg*DIM + db*64 + d)*SEQ*2;        // d-row bytes
    int swz = (seg*8) ^ ((d & 7) << 4);                       // within 128B tile
    *(uint2*)((char*)VT + rowb + rb*128 + swz) = u;
  }

  size_t obase = ((size_t)(bbg*NBLK + rb))*DIM + db*64;
  if (tid < 64){
    float s = 0.f;
#pragma unroll
    for (int i = 0; i < 16; ++i) s += accK[i][tid];
    Kc[obase + tid] = s + b_k[0];
  } else if (tid < 128){
    int d = tid - 64;
    float s = 0.f;
#pragma unroll
    for (int i = 0; i < 16; ++i) s += accV[i][d];
    Vc[obase + d] = s + b_v[0];
  }
}

// ---- kernel 1: rebalanced (cmp+slc[0..16-s)) | (cmp+win+slc[16-s..16)) -----
// grid 256, 512 threads. block = (bbg, qb, role); wave w: head w&3, qhalf w>>2.
// Swapped QK^T: C[col=l15=query][row=quad*4+r=key] -> lane-local softmax.
// Phase t = { stage t+1 | QK_t | rescale+PV_{t-1} | [win-finalize] | softmax_t }.
// V triple-ring; K double-buffer; single P slab per wave.
__global__ __launch_bounds__(512, 2) void attn_k(
    const float* __restrict__ q, const ushort_t* __restrict__ Kb,
    const ushort_t* __restrict__ VT,
    const float* __restrict__ Kc, const float* __restrict__ Vc,
    const float* __restrict__ w_gate, const float* __restrict__ b_gate,
    float* __restrict__ slcbuf, float* __restrict__ out)
{
  int idx = blockIdx.x;             // 256 blocks
  int x = idx & 7, low = idx & 1, u = idx >> 3;
  int bbg = x >> 1;                 // (bb,g): same-bbg blocks share XCD pair
  int j = u*2 + low;                // 0..63
  int role = j >> 5;                // 0 = cmp+slcA, 1 = cmp+win+slcB
  int qb = j & 31;
  int bb = bbg >> 1, g = bbg & 1;

  int tid = threadIdx.x;
  int lane = tid & 63, w = tid >> 6;        // wave 0..7
  int quad = lane >> 4, l15 = lane & 15;
  int h = w & 3, qh2 = w >> 2;              // head, query half
  int xr = (l15 & 7) << 4;                  // read-side XOR (matches prep_k)

  __shared__ ushort_t Ks[2][64*128];    // 32 KB K double buffer
  __shared__ ushort_t VTs[3][128*64];   // 48 KB V triple ring
  __shared__ ushort_t Ps[256*VP];       // 36 KB (per-wave 32-row slabs)
  __shared__ ushort_t VcTh[128*VCS];    // 10 KB cmp V^T hi (role0)
  __shared__ ushort_t VcTl[128*VCS];    // 10 KB cmp V^T lo (role0)
  __shared__ float pw[8][NBLK];         //  1 KB pooled partials per wave
  __shared__ float gbuf[256];           // primary gate per row
  __shared__ float gbuf2[256];          // secondary gate per row
  __shared__ int   idxs[NTOP];

  // ---- stage cmp K tiles (Kc hi/lo -> Ks[0]) for BOTH roles ----
  {
    int key = tid >> 4, dq = tid & 15;          // 32 keys x 16 dim-octets
    const float* kcs = Kc + ((size_t)bbg*NBLK + key)*DIM + dq*8;
    float4 f0 = *(const float4*)kcs, f1 = *(const float4*)(kcs + 4);
    float fe[8] = {f0.x,f0.y,f0.z,f0.w,f1.x,f1.y,f1.z,f1.w};
    union { ushort_t u[8]; uint4 v; } hi, lo;
#pragma unroll
    for (int e = 0; e < 8; ++e){
      ushort_t hh = b16(fe[e]);
      hi.u[e] = hh; lo.u[e] = b16(fe[e] - fb(hh));
    }
    int off = (dq*16) ^ ((key & 7) << 4);
    *(uint4*)((char*)&Ks[0][0] + key*256 + off) = hi.v;
    *(uint4*)((char*)&Ks[0][0] + (key+32)*256 + off) = lo.v;
  }
  // cmp V^T only needed by role0 (cmp-PV emitter)
  if (role == 0){
    int d = tid & 127, kq = tid >> 7;           // 128 dims x 4 key-octets
    const float* vcs = Vc + (size_t)bbg*NBLK*DIM + d;
    union { ushort_t u[8]; uint4 v; } hi, lo;
#pragma unroll
    for (int kk = 0; kk < 8; ++kk){
      float f = vcs[(kq*8 + kk)*DIM];
      ushort_t hh = b16(f);
      hi.u[kk] = hh; lo.u[kk] = b16(f - fb(hh));
    }
    *(uint4*)&VcTh[d*VCS + kq*8] = hi.v;
    *(uint4*)&VcTl[d*VCS + kq*8] = lo.v;
  }

  // ---- Q fragments (hi/lo, pre-scaled by SCALE*log2e) + two gates ------
  const float* qrow0 = q + ((size_t)(bb*SEQ + qb*64 + qh2*32 + l15)*QH + g*NH + h)*DIM;
  const float* qrow1 = qrow0 + (size_t)16*QH*DIM;
  int colA = 1 + role;                 // primary: slc (r0) / win (r1)
  int colB = (role == 0) ? 0 : 1;     // secondary: cmp (r0) / slc (r1)
  bf16x8 qfrag0[4], qfrag1[4], qlo0[4], qlo1[4];
  float gpA0 = 0.f, gpA1 = 0.f, gpB0 = 0.f, gpB1 = 0.f;
#pragma unroll
  for (int kc = 0; kc < 4; ++kc){
    int d0 = kc*32 + quad*8;
    float4 a0 = *(const float4*)(qrow0 + d0);
    float4 a1 = *(const float4*)(qrow0 + d0 + 4);
    float4 b0 = *(const float4*)(qrow1 + d0);
    float4 b1 = *(const float4*)(qrow1 + d0 + 4);
    float qa[8] = {a0.x,a0.y,a0.z,a0.w,a1.x,a1.y,a1.z,a1.w};
    float qc[8] = {b0.x,b0.y,b0.z,b0.w,b1.x,b1.y,b1.z,b1.w};
#pragma unroll
    for (int jj = 0; jj < 8; ++jj){
      float wA = w_gate[(d0+jj)*3 + colA];
      float wB = w_gate[(d0+jj)*3 + colB];
      gpA0 += qa[jj]*wA; gpA1 += qc[jj]*wA;
      gpB0 += qa[jj]*wB; gpB1 += qc[jj]*wB;
    }
    union { ushort_t u[8]; bf16x8 v; } h0, l0, h1, l1;
#pragma unroll
    for (int e = 0; e < 8; ++e){
      float s0f = qa[e]*QSC; ushort_t hh0 = b16(s0f);
      h0.u[e] = hh0; l0.u[e] = b16(s0f - fb(hh0));
      float s1f = qc[e]*QSC; ushort_t hh1 = b16(s1f);
      h1.u[e] = hh1; l1.u[e] = b16(s1f - fb(hh1));
    }
    qfrag0[kc] = h0.v; qlo0[kc] = l0.v;
    qfrag1[kc] = h1.v; qlo1[kc] = l1.v;
  }
  gpA0 += __shfl_xor(gpA0,16); gpA0 += __shfl_xor(gpA0,32);
  gpA1 += __shfl_xor(gpA1,16); gpA1 += __shfl_xor(gpA1,32);
  gpB0 += __shfl_xor(gpB0,16); gpB0 += __shfl_xor(gpB0,32);
  gpB1 += __shfl_xor(gpB1,16); gpB1 += __shfl_xor(gpB1,32);
  if (quad == 0){
    gbuf [w*32 + l15]      = 1.f/(1.f + __expf(-(gpA0 + b_gate[colA])));
    gbuf [w*32 + 16 + l15] = 1.f/(1.f + __expf(-(gpA1 + b_gate[colA])));
    gbuf2[w*32 + l15]      = 1.f/(1.f + __expf(-(gpB0 + b_gate[colB])));
    gbuf2[w*32 + 16 + l15] = 1.f/(1.f + __expf(-(gpB1 + b_gate[colB])));
  }
  __syncthreads();   // publishes gates + cmp tiles
  float gl0[4], gl1[4], gs0[4], gs1[4];
#pragma unroll
  for (int r = 0; r < 4; ++r){
    gl0[r] = gbuf [w*32 + quad*4 + r];
    gl1[r] = gbuf [w*32 + 16 + quad*4 + r];
    gs0[r] = gbuf2[w*32 + quad*4 + r];       // role1: per-row slc gate
    gs1[r] = gbuf2[w*32 + 16 + quad*4 + r];
  }
  float g0c0 = gbuf2[w*32 + l15];            // role0: per-row cmp gate
  float g0c1 = gbuf2[w*32 + 16 + l15];

  const f32x4 zero4 = {0.f,0.f,0.f,0.f};
  f32x4 cp0[2], cp1[2];      // cmp g0*P_norm (role0 only), kept across loop
  cp0[0] = zero4; cp0[1] = zero4; cp1[0] = zero4; cp1[1] = zero4;

  // ======== cmp phase (BOTH roles; bit-identical -> identical topk) =========
  {
    f32x4 c0[2], c1[2];
    c0[0]=zero4; c0[1]=zero4; c1[0]=zero4; c1[1]=zero4;
#pragma unroll
    for (int kc = 0; kc < 4; ++kc){
#pragma unroll
      for (int nt = 0; nt < 2; ++nt){
        bf16x8 ah = *(bf16x8*)((char*)&Ks[0][0] + (nt*16 + l15)*256
                               + ((kc*64 + quad*16) ^ xr));
        bf16x8 al = *(bf16x8*)((char*)&Ks[0][0] + (nt*16 + l15 + 32)*256
                               + ((kc*64 + quad*16) ^ xr));
        c0[nt] = __builtin_amdgcn_mfma_f32_16x16x32_bf16(ah, qfrag0[kc], c0[nt], 0, 0, 0);
        c0[nt] = __builtin_amdgcn_mfma_f32_16x16x32_bf16(ah, qlo0[kc],   c0[nt], 0, 0, 0);
        c0[nt] = __builtin_amdgcn_mfma_f32_16x16x32_bf16(al, qfrag0[kc], c0[nt], 0, 0, 0);
        c1[nt] = __builtin_amdgcn_mfma_f32_16x16x32_bf16(ah, qfrag1[kc], c1[nt], 0, 0, 0);
        c1[nt] = __builtin_amdgcn_mfma_f32_16x16x32_bf16(ah, qlo1[kc],   c1[nt], 0, 0, 0);
        c1[nt] = __builtin_amdgcn_mfma_f32_16x16x32_bf16(al, qfrag1[kc], c1[nt], 0, 0, 0);
      }
    }
    // one-shot softmax over 32 keys (log2 domain)
    float mx0 = -INFINITY, mx1 = -INFINITY;
#pragma unroll
    for (int nt = 0; nt < 2; ++nt)
#pragma unroll
      for (int r = 0; r < 4; ++r){
        mx0 = fmaxf(mx0, c0[nt][r]); mx1 = fmaxf(mx1, c1[nt][r]);
      }
    mx0 = fmaxf(mx0, __shfl_xor(mx0,16)); mx0 = fmaxf(mx0, __shfl_xor(mx0,32));
    mx1 = fmaxf(mx1, __shfl_xor(mx1,16)); mx1 = fmaxf(mx1, __shfl_xor(mx1,32));
    float s0 = 0.f, s1 = 0.f;
#pragma unroll
    for (int nt = 0; nt < 2; ++nt)
#pragma unroll
      for (int r = 0; r < 4; ++r){
        float p0v = exp2f(c0[nt][r] - mx0); c0[nt][r] = p0v; s0 += p0v;
        float p1v = exp2f(c1[nt][r] - mx1); c1[nt][r] = p1v; s1 += p1v;
      }
    s0 += __shfl_xor(s0,16); s0 += __shfl_xor(s0,32);
    s1 += __shfl_xor(s1,16); s1 += __shfl_xor(s1,32);
    float ip0 = 1.f/s0, ip1 = 1.f/s1;
    if (role == 0){
      float ig0 = g0c0*ip0, ig1 = g0c1*ip1;
#pragma unroll
      for (int nt = 0; nt < 2; ++nt)
#pragma unroll
        for (int r = 0; r < 4; ++r){
          cp0[nt][r] = c0[nt][r]*ig0;
          cp1[nt][r] = c1[nt][r]*ig1;
        }
    }
#pragma unroll
    for (int nt = 0; nt < 2; ++nt)
#pragma unroll
      for (int r = 0; r < 4; ++r){
        float t = c0[nt][r]*ip0 + c1[nt][r]*ip1;     // ungated Pn sums
        t += __shfl_xor(t,1); t += __shfl_xor(t,2);
        t += __shfl_xor(t,4); t += __shfl_xor(t,8);
        if (l15 == 0) pw[w][nt*16 + quad*4 + r] = t;
      }
    __syncthreads();   // pw ready
    // top-16 on wave 0: bitonic sort of 32 (desc, tie: lower idx), 15 stages
    if (tid < 64){
      int n = lane;
      float val = -INFINITY;
      if (n < NBLK){
        float sm = 0.f;
#pragma unroll
        for (int w2 = 0; w2 < 8; ++w2) sm += pw[w2][n];
        val = sm;
      }
      int idxv = n;
      for (int kk = 2; kk <= 32; kk <<= 1){
        for (int jj2 = kk >> 1; jj2 > 0; jj2 >>= 1){
          float pv = __shfl_xor(val, jj2);
          int   pi = __shfl_xor(idxv, jj2);
          bool lower = (lane & jj2) == 0;
          bool desc  = (lane & kk) == 0;
          bool iwin  = (val > pv) || (val == pv && idxv < pi);
          bool keep  = (lower == desc) ? iwin : !iwin;
          if (!keep){ val = pv; idxv = pi; }
        }
      }
      if (lane < NTOP) idxs[lane] = idxv;
    }
    __syncthreads();   // idxs ready; cmp reads of Ks[0] done -> restage ok
  }

  const ushort_t* kbase  = Kb + (size_t)bbg*SEQ*DIM;
  const ushort_t* vtbase = VT + (size_t)bbg*DIM*SEQ;

  int kb0  = (qb >= 8) ? (qb - 8) : 0;
  int nwin = qb - kb0 + 1;                  // 1..9
  int s    = (17 - nwin) >> 1;              // role1 slc tiles (4..8)
  int nslc0 = 16 - s;                       // role0 slc tiles (8..12)
  int nph  = (role == 0) ? nslc0 : (nwin + s);
  int qi0 = qh2*32 + l15, qi1 = qi0 + 16;   // lane-local query indices

  auto tsel = [&](int t)->int {
    if (role == 0) return idxs[t];
    return (t < nwin) ? (kb0 + t) : idxs[nslc0 + (t - nwin)];
  };

  float m10 = -INFINITY, l10 = 0.f, m11 = -INFINITY, l11 = 0.f;
  f32x4 oacc0[8], oacc1[8];
#pragma unroll
  for (int dt = 0; dt < 8; ++dt){ oacc0[dt] = zero4; oacc1[dt] = zero4; }

  // staging: 512 threads x 2 units x 16B per tile; LDS dest linear
  auto stage = [&](int kbuf, int vbuf, int kb_){
    const ushort_t* ksrc = kbase + (size_t)kb_*64*DIM;
#pragma unroll
    for (int jj = 0; jj < 2; ++jj)          // K tile: 1024 16B units
      async16(&Ks[kbuf][(jj*512 + w*64)*8], ksrc + (size_t)(tid + jj*512)*8);
    const ushort_t* vsrc = vtbase + kb_*64;
#pragma unroll
    for (int jj = 0; jj < 2; ++jj){         // VT tile: [d=128][64]
      int i = tid + jj*512;
      int d = i >> 3, sg = i & 7;
      async16(&VTs[vbuf][(jj*512 + w*64)*8], vsrc + (size_t)d*SEQ + sg*8);
    }
  };

  stage(0, 0, tsel(0));

  float alp0 = 1.f, alp1 = 1.f;
  bool  skp0 = true,  skp1 = true;
  int vprev = 2, vcur = 0, vnext = 1;       // V ring indices

  for (int t = 0; t < nph; ++t){
    int kb = tsel(t);
    // vmcnt(0)+lgkmcnt(0) drain + barrier: tile t resident; old bufs free.
    __syncthreads();
    if (t+1 < nph) stage((t+1) & 1, vnext, tsel(t+1));
    __builtin_amdgcn_sched_barrier(0);      // pin prefetch issue early

    // ---- QK_t swapped: mfma(K, Q) ----
    f32x4 sacc0[4], sacc1[4];
#pragma unroll
    for (int nt = 0; nt < 4; ++nt){ sacc0[nt] = zero4; sacc1[nt] = zero4; }
    __builtin_amdgcn_s_setprio(1);
#pragma unroll
    for (int kc = 0; kc < 4; ++kc){
#pragma unroll
      for (int nt = 0; nt < 4; ++nt){
        bf16x8 a = *(bf16x8*)((char*)&Ks[t & 1][0] + (nt*16 + l15)*256
                              + ((kc*64 + quad*16) ^ xr));
        sacc0[nt] = __builtin_amdgcn_mfma_f32_16x16x32_bf16(a, qfrag0[kc], sacc0[nt], 0, 0, 0);
        sacc1[nt] = __builtin_amdgcn_mfma_f32_16x16x32_bf16(a, qfrag1[kc], sacc1[nt], 0, 0, 0);
      }
    }
    __builtin_amdgcn_s_setprio(0);

    // ---- deferred: rescale O by alpha_{t-1}, then PV_{t-1} ----
    if (t > 0){
      if (!skp0){
        float ar[4];
#pragma unroll
        for (int r = 0; r < 4; ++r) ar[r] = __shfl(alp0, quad*4 + r);
#pragma unroll
        for (int dt = 0; dt < 8; ++dt)
#pragma unroll
          for (int r = 0; r < 4; ++r) oacc0[dt][r] *= ar[r];
      }
      if (!skp1){
        float ar[4];
#pragma unroll
        for (int r = 0; r < 4; ++r) ar[r] = __shfl(alp1, quad*4 + r);
#pragma unroll
        for (int dt = 0; dt < 8; ++dt)
#pragma unroll
          for (int r = 0; r < 4; ++r) oacc1[dt][r] *= ar[r];
      }
#pragma unroll
      for (int kc2 = 0; kc2 < 2; ++kc2){
        bf16x8 pa0 = *(bf16x8*)&Ps[(w*32 + l15)*VP + kc2*32 + quad*8];
        bf16x8 pa1 = *(bf16x8*)&Ps[(w*32 + 16 + l15)*VP + kc2*32 + quad*8];
        __builtin_amdgcn_s_setprio(1);
#pragma unroll
        for (int dt = 0; dt < 8; ++dt){
          bf16x8 vb8 = *(bf16x8*)((char*)&VTs[vprev][0] + (dt*16 + l15)*128
                                  + ((kc2*64 + quad*16) ^ xr));
          oacc0[dt] = __builtin_amdgcn_mfma_f32_16x16x32_bf16(pa0, vb8, oacc0[dt], 0, 0, 0);
          oacc1[dt] = __builtin_amdgcn_mfma_f32_16x16x32_bf16(pa1, vb8, oacc1[dt], 0, 0, 0);
        }
        __builtin_amdgcn_s_setprio(0);
      }
    }

    // ---- role1 @ t==nwin: finalize win (normalize+gate -> g_winB), reset ----
    if (role == 1 && t == nwin){
      float lr0f[4], lr1f[4];
#pragma unroll
      for (int r = 0; r < 4; ++r){
        lr0f[r] = __shfl(l10, quad*4 + r);
        lr1f[r] = __shfl(l11, quad*4 + r);
      }
#pragma unroll
      for (int r = 0; r < 4; ++r){
        float s20 = gl0[r] / lr0f[r];
        float s21 = gl1[r] / lr1f[r];
        size_t ob0 = ((size_t)(bb*SEQ + qb*64 + qh2*32 + quad*4 + r)*QH + g*NH + h)*DIM + l15;
        size_t ob1 = ob0 + (size_t)16*QH*DIM;
#pragma unroll
        for (int dt = 0; dt < 8; ++dt){
          g_winB[ob0 + dt*16] = s20 * oacc0[dt][r];
          g_winB[ob1 + dt*16] = s21 * oacc1[dt][r];
        }
      }
#pragma unroll
      for (int dt = 0; dt < 8; ++dt){ oacc0[dt] = zero4; oacc1[dt] = zero4; }
      m10 = -INFINITY; l10 = 0.f; m11 = -INFINITY; l11 = 0.f;
      alp0 = 1.f; skp0 = true; alp1 = 1.f; skp1 = true;
    }

    // ---- softmax_t (log2 domain; tree max/sum; defer-max) ----
    bool winph = (role == 1) && (t < nwin);
    bool mlow  = winph && (kb == qb - 8);   // valid: key >= qi
    bool mhigh = winph && (kb == qb);       // valid: key <= qi
    bool domask = mlow | mhigh;

    auto softmax_qt = [&](f32x4* sc2, float& m1r, float& l1r, int qi_l,
                          bool& skipped) -> float {
      if (domask){
#pragma unroll
        for (int nt = 0; nt < 4; ++nt)
#pragma unroll
          for (int r = 0; r < 4; ++r){
            int key = nt*16 + quad*4 + r;
            bool valid = (!mlow || key >= qi_l) && (!mhigh || key <= qi_l);
            sc2[nt][r] = valid ? sc2[nt][r] : -INFINITY;
          }
      }
      float mnt[4];
#pragma unroll
      for (int nt = 0; nt < 4; ++nt)
        mnt[nt] = fmaxf(fmaxf(sc2[nt][0], sc2[nt][1]),
                        fmaxf(sc2[nt][2], sc2[nt][3]));
      float mx = fmaxf(fmaxf(mnt[0], mnt[1]), fmaxf(mnt[2], mnt[3]));
      mx = fmaxf(mx, __shfl_xor(mx, 16));
      mx = fmaxf(mx, __shfl_xor(mx, 32));
      float al = 1.f;
      skipped = __all(mx <= m1r + 8.f);     // defer-max: P bounded by 2^8
      if (!skipped){
        float mn = fmaxf(m1r, mx);
        al = exp2f(m1r - mn);
        m1r = mn;
      }
      float snt[4];
#pragma unroll
      for (int nt = 0; nt < 4; ++nt){
        float p0 = exp2f(sc2[nt][0] - m1r);
        float p1 = exp2f(sc2[nt][1] - m1r);
        float p2 = exp2f(sc2[nt][2] - m1r);
        float p3 = exp2f(sc2[nt][3] - m1r);
        sc2[nt][0] = p0; sc2[nt][1] = p1; sc2[nt][2] = p2; sc2[nt][3] = p3;
        snt[nt] = (p0 + p1) + (p2 + p3);
      }
      float s0 = (snt[0] + snt[1]) + (snt[2] + snt[3]);
      s0 += __shfl_xor(s0, 16);
      s0 += __shfl_xor(s0, 32);
      l1r = l1r*al + s0;
      return al;
    };
    bool sk0, sk1;
    float al0 = softmax_qt(sacc0, m10, l10, qi0, sk0);
    float al1 = softmax_qt(sacc1, m11, l11, qi1, sk1);
    alp0 = al0; skp0 = sk0;
    alp1 = al1; skp1 = sk1;

    // ---- P -> LDS bf16, packed b64 (row = query; wave-private slab) ----
#pragma unroll
    for (int nt = 0; nt < 4; ++nt){
      uint2 p0, p1;
      p0.x = pkbf(sacc0[nt][0], sacc0[nt][1]);
      p0.y = pkbf(sacc0[nt][2], sacc0[nt][3]);
      p1.x = pkbf(sacc1[nt][0], sacc1[nt][1]);
      p1.y = pkbf(sacc1[nt][2], sacc1[nt][3]);
      *(uint2*)&Ps[(w*32 + l15)*VP + nt*16 + quad*4] = p0;
      *(uint2*)&Ps[(w*32 + 16 + l15)*VP + nt*16 + quad*4] = p1;
    }

    int tmpv = vprev; vprev = vcur; vcur = vnext; vnext = tmpv;
  }

  // ---- drain: rescale + PV_{nph-1} ----
  {
    if (!skp0){
      float ar[4];
#pragma unroll
      for (int r = 0; r < 4; ++r) ar[r] = __shfl(alp0, quad*4 + r);
#pragma unroll
      for (int dt = 0; dt < 8; ++dt)
#pragma unroll
        for (int r = 0; r < 4; ++r) oacc0[dt][r] *= ar[r];
    }
    if (!skp1){
      float ar[4];
#pragma unroll
      for (int r = 0; r < 4; ++r) ar[r] = __shfl(alp1, quad*4 + r);
#pragma unroll
      for (int dt = 0; dt < 8; ++dt)
#pragma unroll
        for (int r = 0; r < 4; ++r) oacc1[dt][r] *= ar[r];
    }
#pragma unroll
    for (int kc2 = 0; kc2 < 2; ++kc2){
      bf16x8 pa0 = *(bf16x8*)&Ps[(w*32 + l15)*VP + kc2*32 + quad*8];
      bf16x8 pa1 = *(bf16x8*)&Ps[(w*32 + 16 + l15)*VP + kc2*32 + quad*8];
#pragma unroll
      for (int dt = 0; dt < 8; ++dt){
        bf16x8 vb8 = *(bf16x8*)((char*)&VTs[vprev][0] + (dt*16 + l15)*128
                                + ((kc2*64 + quad*16) ^ xr));
        oacc0[dt] = __builtin_amdgcn_mfma_f32_16x16x32_bf16(pa0, vb8, oacc0[dt], 0, 0, 0);
        oacc1[dt] = __builtin_amdgcn_mfma_f32_16x16x32_bf16(pa1, vb8, oacc1[dt], 0, 0, 0);
      }
    }
  }

  // ---- epilogue ----
  size_t rh0 = ((size_t)(bb*SEQ + qb*64 + qh2*32 + l15)*QH + g*NH + h);
  size_t rh1 = rh0 + (size_t)16*QH;
  if (role == 0){
    // raw gated slc partial -> slcbuf, (m,l) -> g_mlg[0]
#pragma unroll
    for (int r = 0; r < 4; ++r){
      size_t ob0 = ((size_t)(bb*SEQ + qb*64 + qh2*32 + quad*4 + r)*QH + g*NH + h)*DIM + l15;
      size_t ob1 = ob0 + (size_t)16*QH*DIM;
#pragma unroll
      for (int dt = 0; dt < 8; ++dt){
        slcbuf[ob0 + dt*16] = gl0[r] * oacc0[dt][r];
        slcbuf[ob1 + dt*16] = gl1[r] * oacc1[dt][r];
      }
    }
    if (quad == 0){
      g_mlg[0][rh0*2] = m10; g_mlg[0][rh0*2 + 1] = l10;
      g_mlg[0][rh1*2] = m11; g_mlg[0][rh1*2 + 1] = l11;
    }
    // cmp-PV into fresh acc -> out (overwrite; first branch)
#pragma unroll
    for (int dt = 0; dt < 8; ++dt){ oacc0[dt] = zero4; oacc1[dt] = zero4; }
#pragma unroll
    for (int nt = 0; nt < 2; ++nt){
      union { ushort_t u[4]; uint2 v; } h0, l0, h1, l1;
#pragma unroll
      for (int r = 0; r < 4; ++r){
        ushort_t hh0 = b16(cp0[nt][r]);
        h0.u[r] = hh0; l0.u[r] = b16(cp0[nt][r] - fb(hh0));
        ushort_t hh1 = b16(cp1[nt][r]);
        h1.u[r] = hh1; l1.u[r] = b16(cp1[nt][r] - fb(hh1));
      }
      *(uint2*)&Ps[(w*32 + l15)*VP + nt*16 + quad*4]      = h0.v;
      *(uint2*)&Ps[(w*32 + l15)*VP + 32 + nt*16 + quad*4] = l0.v;
      *(uint2*)&Ps[(w*32 + 16 + l15)*VP + nt*16 + quad*4]      = h1.v;
      *(uint2*)&Ps[(w*32 + 16 + l15)*VP + 32 + nt*16 + quad*4] = l1.v;
    }
    bf16x8 pah0 = *(bf16x8*)&Ps[(w*32 + l15)*VP + quad*8];
    bf16x8 pal0 = *(bf16x8*)&Ps[(w*32 + l15)*VP + 32 + quad*8];
    bf16x8 pah1 = *(bf16x8*)&Ps[(w*32 + 16 + l15)*VP + quad*8];
    bf16x8 pal1 = *(bf16x8*)&Ps[(w*32 + 16 + l15)*VP + 32 + quad*8];
#pragma unroll
    for (int dt = 0; dt < 8; ++dt){
      bf16x8 vbh = *(bf16x8*)&VcTh[(dt*16 + l15)*VCS + quad*8];
      bf16x8 vbl = *(bf16x8*)&VcTl[(dt*16 + l15)*VCS + quad*8];
      oacc0[dt] = __builtin_amdgcn_mfma_f32_16x16x32_bf16(pah0, vbh, oacc0[dt], 0, 0, 0);
      oacc0[dt] = __builtin_amdgcn_mfma_f32_16x16x32_bf16(pah0, vbl, oacc0[dt], 0, 0, 0);
      oacc0[dt] = __builtin_amdgcn_mfma_f32_16x16x32_bf16(pal0, vbh, oacc0[dt], 0, 0, 0);
      oacc1[dt] = __builtin_amdgcn_mfma_f32_16x16x32_bf16(pah1, vbh, oacc1[dt], 0, 0, 0);
      oacc1[dt] = __builtin_amdgcn_mfma_f32_16x16x32_bf16(pah1, vbl, oacc1[dt], 0, 0, 0);
      oacc1[dt] = __builtin_amdgcn_mfma_f32_16x16x32_bf16(pal1, vbh, oacc1[dt], 0, 0, 0);
    }
#pragma unroll
    for (int r = 0; r < 4; ++r){
      size_t ob0 = ((size_t)(bb*SEQ + qb*64 + qh2*32 + quad*4 + r)*QH + g*NH + h)*DIM + l15;
      size_t ob1 = ob0 + (size_t)16*QH*DIM;
#pragma unroll
      for (int dt = 0; dt < 8; ++dt){
        out[ob0 + dt*16] = oacc0[dt][r];
        out[ob1 + dt*16] = oacc1[dt][r];
      }
    }
  } else {
    // raw gated slc partial (slc gate = gs) -> g_slcB, (m,l) -> g_mlg[1]
#pragma unroll
    for (int r = 0; r < 4; ++r){
      size_t ob0 = ((size_t)(bb*SEQ + qb*64 + qh2*32 + quad*4 + r)*QH + g*NH + h)*DIM + l15;
      size_t ob1 = ob0 + (size_t)16*QH*DIM;
#pragma unroll
      for (int dt = 0; dt < 8; ++dt){
        g_slcB[ob0 + dt*16] = gs0[r] * oacc0[dt][r];
        g_slcB[ob1 + dt*16] = gs1[r] * oacc1[dt][r];
      }
    }
    if (quad == 0){
      g_mlg[1][rh0*2] = m10; g_mlg[1][rh0*2 + 1] = l10;
      g_mlg[1][rh1*2] = m11; g_mlg[1][rh1*2 + 1] = l11;
    }
  }
}

// ------ kernel 2: merge (flash-combine slc halves + win + cmp) --------------
__global__ __launch_bounds__(256) void merge_k(const float* __restrict__ slcA,
                                               float* __restrict__ out){
  // 1,048,576 float4s; 2048 blocks x 256 thr x 2 each
  int base = blockIdx.x * 512 + threadIdx.x;
#pragma unroll
  for (int jj = 0; jj < 2; ++jj){
    int i = base + jj*256;
    int rh = i >> 5;
    float mA = g_mlg[0][rh*2], lA = g_mlg[0][rh*2+1];
    float mB = g_mlg[1][rh*2], lB = g_mlg[1][rh*2+1];
    float M  = fmaxf(mA, mB);
    float wA = exp2f(mA - M), wB = exp2f(mB - M);
    float inv = 1.f/(lA*wA + lB*wB);
    float4 a = ((const float4*)slcA)[i];
    float4 b = ((const float4*)g_slcB)[i];
    float4 wn = ((const float4*)g_winB)[i];
    float4 o = ((float4*)out)[i];                 // cmp branch
    o.x += wn.x + (a.x*wA + b.x*wB)*inv;
    o.y += wn.y + (a.y*wA + b.y*wB)*inv;
    o.z += wn.z + (a.z*wA + b.z*wB)*inv;
    o.w += wn.w + (a.w*wA + b.w*wB)*inv;
    ((float4*)out)[i] = o;
  }
}

extern "C" void kernel_launch(void* const* d_in, const int* in_sizes, int n_in,
                              void* d_out, int out_size, void* d_ws, size_t ws_size,
                              hipStream_t stream) {
  const float* q      = (const float*)d_in[0];
  const float* k      = (const float*)d_in[1];
  const float* v      = (const float*)d_in[2];
  const float* w_k    = (const float*)d_in[3];
  const float* b_k    = (const float*)d_in[4];
  const float* w_v    = (const float*)d_in[5];
  const float* b_v    = (const float*)d_in[6];
  const float* w_gate = (const float*)d_in[7];
  const float* b_gate = (const float*)d_in[8];
  float* out = (float*)d_out;

  float* ws     = (float*)d_ws;
  float* Kc     = ws;                        // 16384 f32
  float* Vc     = ws + 16384;                // 16384 f32
  float* slcbuf = ws + 49152;                // 4.19M f32 (16.8 MB)
  ushort_t* Kb  = (ushort_t*)(ws + 4243456); // 4*2048*128 bf16 (2 MB)
  ushort_t* VT  = Kb + 1048576;              // 4*128*2048 bf16 (2 MB)

  prep_k <<<256, 256, 0, stream>>>(k, v, w_k, b_k, w_v, b_v, Kb, VT, Kc, Vc);
  attn_k <<<256, 512, 0, stream>>>(q, Kb, VT, Kc, Vc, w_gate, b_gate, slcbuf, out);
  merge_k<<<2048, 256, 0, stream>>>(slcbuf, out);
}